// Round 11
// baseline (270.096 us; speedup 1.0000x reference)
//
#include <hip/hip_runtime.h>
#include <hip/hip_bf16.h>
#include <math.h>

#define BATCH 4
#define SEQ   2048
#define DM    1024
#define NH    16
#define DH    64

// log2(e) / sqrt(DH)
#define QSCALE 0.1803368801111204f

typedef __bf16 bf16x8 __attribute__((ext_vector_type(8)));
typedef __bf16 bf16x4 __attribute__((ext_vector_type(4)));
typedef float  f32x4  __attribute__((ext_vector_type(4)));

typedef const __attribute__((address_space(1))) unsigned int guint;
typedef __attribute__((address_space(3)))       unsigned int luint;

// async global->LDS, 16 B/lane, wave-uniform LDS base + lane*16
__device__ __forceinline__ void async16(const __bf16* g, __bf16* l) {
    __builtin_amdgcn_global_load_lds((guint*)g, (luint*)l, 16, 0, 0);
}

// raw v_exp_f32 (2^x)
__device__ __forceinline__ float fast_exp2(float x) {
#if __has_builtin(__builtin_amdgcn_exp2f)
    return __builtin_amdgcn_exp2f(x);
#else
    float r; asm("v_exp_f32 %0, %1" : "=v"(r) : "v"(x)); return r;
#endif
}
// raw v_rcp_f32
__device__ __forceinline__ float fast_rcp(float x) {
#if __has_builtin(__builtin_amdgcn_rcpf)
    return __builtin_amdgcn_rcpf(x);
#else
    float r; asm("v_rcp_f32 %0, %1" : "=v"(r) : "v"(x)); return r;
#endif
}

// Load 8 consecutive fp32 elements, convert to bf16x8 (RNE).
__device__ __forceinline__ bf16x8 load8f(const float* __restrict__ base, size_t idx) {
    const float4 a = *(const float4*)(base + idx);
    const float4 b = *(const float4*)(base + idx + 4);
    bf16x8 r;
    r[0] = (__bf16)a.x; r[1] = (__bf16)a.y; r[2] = (__bf16)a.z; r[3] = (__bf16)a.w;
    r[4] = (__bf16)b.x; r[5] = (__bf16)b.y; r[6] = (__bf16)b.z; r[7] = (__bf16)b.w;
    return r;
}

// ---------------------------------------------------------------------------
// Kernel 0: fused prep — xconv (blocks 0..4095), Wq/Wk/Wv transpose
// (blocks 4096..4863), Wo transpose (blocks 4864..5119).
// Wqt/Wkt/Wvt contiguous => Wcat[3072][1024] for qkv_gemm.
// (unchanged — control)
// ---------------------------------------------------------------------------
__global__ __launch_bounds__(256)
void prep_kernel(const float* __restrict__ X,
                 const float* __restrict__ Wq,
                 const float* __restrict__ Wk,
                 const float* __restrict__ Wv,
                 const float* __restrict__ Wo,
                 __bf16* __restrict__ Xb,
                 __bf16* __restrict__ Wqt,
                 __bf16* __restrict__ Wkt,
                 __bf16* __restrict__ Wvt,
                 __bf16* __restrict__ Wot)
{
    __shared__ __bf16 T[64][65];
    const int t  = threadIdx.x;
    const int bx = blockIdx.x;

    if (bx < 4096) {                       // ---- xconv: X fp32 -> bf16
        size_t idx = ((size_t)bx * 256 + t) * 8;
        *(bf16x8*)&Xb[idx] = load8f(X, idx);
        return;
    }

    const float* src;
    __bf16* dst;
    int k0, n0, srcN;
    if (bx < 4096 + 768) {                 // ---- Wq/Wk/Wv transpose
        const int i = bx - 4096;
        const int z = i >> 4;              // 0..47
        const int m = z >> 4;              // 0..2
        const int h = z & 15;
        src  = (m == 0 ? Wq : m == 1 ? Wk : Wv) + (size_t)h * DM * DH;
        dst  = (m == 0 ? Wqt : m == 1 ? Wkt : Wvt) + (size_t)h * DH * DM;
        k0   = (i & 15) * 64;
        n0   = 0;
        srcN = DH;
    } else {                               // ---- Wo transpose
        const int i = bx - 4096 - 768;
        src  = Wo;
        dst  = Wot;
        k0   = (i & 15) * 64;
        n0   = (i >> 4) * 64;
        srcN = DM;
    }

#pragma unroll
    for (int i = 0; i < 4; ++i) {
        int row = i * 16 + (t >> 4);
        int col = (t & 15) * 4;
        float4 v = *(const float4*)&src[(size_t)(k0 + row) * srcN + n0 + col];
        T[col + 0][row] = (__bf16)v.x;
        T[col + 1][row] = (__bf16)v.y;
        T[col + 2][row] = (__bf16)v.z;
        T[col + 3][row] = (__bf16)v.w;
    }
    __syncthreads();
#pragma unroll
    for (int i = 0; i < 4; ++i) {
        int n  = i * 16 + (t >> 4);
        int kc = (t & 15) * 4;
        bf16x4 v;
        v[0] = T[n][kc + 0]; v[1] = T[n][kc + 1];
        v[2] = T[n][kc + 2]; v[3] = T[n][kc + 3];
        *(bf16x4*)&dst[(size_t)(n0 + n) * DM + k0 + kc] = v;
    }
}

// ---------------------------------------------------------------------------
// Kernel 1: QKV projection as ONE GEMM  C[8192][3072] = Xb · Wcat^T.
// R1/R9 body. XCD locality via LAUNCH-SIDE grid shape only (the mechanism
// that passed in R9): grid dim3(24, 64), colTile = blockIdx.x,
// rowTile = blockIdx.y. Linear id = x + 24y, 24 % 8 == 0 => XCD = x % 8 =
// colTile % 8: each XCD owns colTiles {r, r+8, r+16} (one Q, one K, one V
// panel, 768 KB of Wcat pinned in its L2). No in-kernel remap arithmetic
// (the R8/R10 deterministic-failure suspect is gone).
// ---------------------------------------------------------------------------
__global__ __launch_bounds__(256)
void qkv_gemm(const __bf16* __restrict__ Xb,
              const __bf16* __restrict__ Wcat,
              __bf16* __restrict__ Qo,
              __bf16* __restrict__ Ko,
              __bf16* __restrict__ Vto)
{
    const int colTile = blockIdx.x;  // 0..23  (fast dim -> XCD = colTile%8)
    const int rowTile = blockIdx.y;  // 0..63
    const int r0 = rowTile * 128;
    const int n0 = colTile * 128;

    __shared__ __align__(16) __bf16 SM[8192];   // As = SM[0..4095], Bs = SM[4096..8191]
    __bf16* As = SM;
    __bf16* Bs = SM + 4096;

    const int t    = threadIdx.x;
    const int wave = t >> 6;
    const int lane = t & 63;
    const int l15  = lane & 15;
    const int quad = lane >> 4;

    f32x4 acc[2][8];
#pragma unroll
    for (int s = 0; s < 2; ++s)
#pragma unroll
        for (int i = 0; i < 8; ++i) acc[s][i] = (f32x4){0.f, 0.f, 0.f, 0.f};

    const int lrow = lane >> 2;
    const int lcol = (lane & 3) * 8;

    for (int k0 = 0; k0 < DM; k0 += 32) {
        __syncthreads();
#pragma unroll
        for (int c = 0; c < 2; ++c) {
            const int rb = wave * 32 + c * 16;
            async16(&Xb  [(size_t)(r0 + rb + lrow) * DM + k0 + lcol], &As[rb * 32]);
            async16(&Wcat[(size_t)(n0 + rb + lrow) * DM + k0 + lcol], &Bs[rb * 32]);
        }
        __syncthreads();

        bf16x8 a0 = *(const bf16x8*)&As[(wave * 16 + l15) * 32 + quad * 8];
        bf16x8 a1 = *(const bf16x8*)&As[(64 + wave * 16 + l15) * 32 + quad * 8];
#pragma unroll
        for (int ct = 0; ct < 8; ++ct) {
            bf16x8 bb = *(const bf16x8*)&Bs[(ct * 16 + l15) * 32 + quad * 8];
            acc[0][ct] = __builtin_amdgcn_mfma_f32_16x16x32_bf16(a0, bb, acc[0][ct], 0, 0, 0);
            acc[1][ct] = __builtin_amdgcn_mfma_f32_16x16x32_bf16(a1, bb, acc[1][ct], 0, 0, 0);
        }
    }

    // ---- epilogue: block-uniform dispatch on destination matrix
    const int mat = colTile >> 3;   // 0=Q, 1=K, 2=V
    if (mat < 2) {
        __bf16* __restrict__ Dst = (mat == 0) ? Qo : Ko;
        const float scale = (mat == 0) ? QSCALE : 1.0f;
        __syncthreads();                          // all waves done reading As/Bs
        char* slab = (char*)SM + wave * 4096;     // wave-private [16][128] bf16 tile
        const int nb = n0 & 1023;                 // column base within the matrix
#pragma unroll
        for (int st = 0; st < 2; ++st) {
            // scatter acc into swizzled slab (scalar LDS writes)
#pragma unroll
            for (int ct = 0; ct < 8; ++ct)
#pragma unroll
                for (int reg = 0; reg < 4; ++reg) {
                    const int row = quad * 4 + reg;
                    *(__bf16*)(slab + row * 256 +
                               (((ct * 16 + l15) * 2) ^ ((row & 7) << 4))) =
                        (__bf16)(acc[st][ct][reg] * scale);
                }
            // read back row-major (wave-private: DS ops in-order) and store
            // coalesced 16 B/lane
#pragma unroll
            for (int i = 0; i < 4; ++i) {
                const int row = i * 4 + quad;
                bf16x8 w = *(const bf16x8*)(slab + row * 256 +
                                            ((l15 * 16) ^ ((row & 7) << 4)));
                const int rg = r0 + st * 64 + wave * 16 + row;
                const int b  = rg >> 11;
                const int s  = rg & (SEQ - 1);
                const int nn = nb + l15 * 8;
                const int h  = nn >> 6;
                const int d  = nn & 63;
                *(bf16x8*)&Dst[(((size_t)(b * NH + h)) * SEQ + s) * DH + d] = w;
            }
        }
    } else {
#pragma unroll
        for (int st = 0; st < 2; ++st) {
            const int r = r0 + st * 64 + wave * 16 + quad * 4;
            const int b = r >> 11;
            const int s = r & (SEQ - 1);
#pragma unroll
            for (int ct = 0; ct < 8; ++ct) {
                const int n = (n0 + ct * 16 + l15) & 1023;
                const int h = n >> 6;
                const int d = n & 63;
                bf16x4 vv;
                vv[0] = (__bf16)acc[st][ct][0]; vv[1] = (__bf16)acc[st][ct][1];
                vv[2] = (__bf16)acc[st][ct][2]; vv[3] = (__bf16)acc[st][ct][3];
                *(bf16x4*)&Vto[(((size_t)(b * NH + h)) * DH + d) * SEQ + s] = vv;
            }
        }
    }
}

// ---------------------------------------------------------------------------
// Kernel 2: causal flash attention — EXACT R9 kernel (79.0 µs, FETCH 37 MB,
// passed). Grid (bh=64, x=16): XCD = bh%8 colocates all 16 blocks of a bh.
// (unchanged — canary: must stay ~79 µs / 37 MB)
// ---------------------------------------------------------------------------
__global__ __launch_bounds__(256)
void attn_kernel(const __bf16* __restrict__ Q,
                 const __bf16* __restrict__ K,
                 const __bf16* __restrict__ Vt,
                 __bf16* __restrict__ Cat)
{
    const int bh  = blockIdx.x;       // 0..63  (fast dim -> XCD = bh%8)
    const int x   = blockIdx.y;       // 0..15
    const int qtA = x;                // light tile
    const int qtB = 31 - x;           // heavy tile
    const int b   = bh >> 4;
    const int h   = bh & 15;

    const __bf16* Qg  = Q  + (size_t)bh * SEQ * DH;
    const __bf16* Kg  = K  + (size_t)bh * SEQ * DH;
    const __bf16* Vtg = Vt + (size_t)bh * DH * SEQ;

    __shared__ __align__(16) __bf16 Ks[64 * 72];
    __shared__ __align__(16) __bf16 Vs[64 * 72];
    __shared__ __align__(16) __bf16 Ps[64 * 72];

    const int t    = threadIdx.x;
    const int wave = t >> 6;
    const int lane = t & 63;
    const int l15  = lane & 15;
    const int quad = lane >> 4;

    bf16x8 qfA[2], qfB[2];
    {
        const size_t rA = (size_t)(qtA * 64 + wave * 16 + l15);
        qfA[0] = *(const bf16x8*)&Qg[rA * DH + quad * 8];
        qfA[1] = *(const bf16x8*)&Qg[rA * DH + 32 + quad * 8];
        const size_t rB = (size_t)(qtB * 64 + wave * 16 + l15);
        qfB[0] = *(const bf16x8*)&Qg[rB * DH + quad * 8];
        qfB[1] = *(const bf16x8*)&Qg[rB * DH + 32 + quad * 8];
    }

    bf16x8 ones;
#pragma unroll
    for (int j = 0; j < 8; ++j) ones[j] = (__bf16)1.0f;

    f32x4 oA[4], oB[4], olA, olB;
#pragma unroll
    for (int ct = 0; ct < 4; ++ct) {
        oA[ct] = (f32x4){0.f, 0.f, 0.f, 0.f};
        oB[ct] = (f32x4){0.f, 0.f, 0.f, 0.f};
    }
    olA = (f32x4){0.f, 0.f, 0.f, 0.f};
    olB = (f32x4){0.f, 0.f, 0.f, 0.f};

    const int srow0 = t >> 3;
    const int scol  = (t & 7) * 8;
    bf16x8 kreg[2], vreg[2];
#pragma unroll
    for (int i = 0; i < 2; ++i) {
        int row = srow0 + i * 32;
        kreg[i] = *(const bf16x8*)&Kg[(size_t)row * DH + scol];
        vreg[i] = *(const bf16x8*)&Vtg[(size_t)row * SEQ + scol];
    }

    auto half_step = [&](const bf16x8* qf, f32x4* o, f32x4& ol, bool diag) {
        f32x4 sc[4];
        __builtin_amdgcn_s_setprio(1);
#pragma unroll
        for (int ct = 0; ct < 4; ++ct) {
            sc[ct] = (f32x4){0.f, 0.f, 0.f, 0.f};
            bf16x8 b0 = *(const bf16x8*)&Ks[(ct * 16 + l15) * 72 + quad * 8];
            sc[ct] = __builtin_amdgcn_mfma_f32_16x16x32_bf16(qf[0], b0, sc[ct], 0, 0, 0);
            bf16x8 b1 = *(const bf16x8*)&Ks[(ct * 16 + l15) * 72 + 32 + quad * 8];
            sc[ct] = __builtin_amdgcn_mfma_f32_16x16x32_bf16(qf[1], b1, sc[ct], 0, 0, 0);
        }
        __builtin_amdgcn_s_setprio(0);
        if (diag) {
#pragma unroll
            for (int ct = 0; ct < 4; ++ct)
#pragma unroll
                for (int r = 0; r < 4; ++r) {
                    int qr = wave * 16 + quad * 4 + r;
                    int kc = ct * 16 + l15;
                    if (kc > qr) sc[ct][r] = -INFINITY;
                }
        }
#pragma unroll
        for (int ct = 0; ct < 4; ++ct)
#pragma unroll
            for (int r = 0; r < 4; ++r)
                sc[ct][r] = fast_exp2(sc[ct][r]);

#pragma unroll
        for (int ct = 0; ct < 4; ++ct)
#pragma unroll
            for (int r = 0; r < 4; ++r)
                Ps[(wave * 16 + quad * 4 + r) * 72 + ct * 16 + l15] =
                    (__bf16)sc[ct][r];

        bf16x8 af0 = *(const bf16x8*)&Ps[(wave * 16 + l15) * 72 + quad * 8];
        bf16x8 af1 = *(const bf16x8*)&Ps[(wave * 16 + l15) * 72 + 32 + quad * 8];

        __builtin_amdgcn_s_setprio(1);
#pragma unroll
        for (int ct = 0; ct < 4; ++ct) {
            bf16x8 v0 = *(const bf16x8*)&Vs[(ct * 16 + l15) * 72 + quad * 8];
            o[ct] = __builtin_amdgcn_mfma_f32_16x16x32_bf16(af0, v0, o[ct], 0, 0, 0);
            bf16x8 v1 = *(const bf16x8*)&Vs[(ct * 16 + l15) * 72 + 32 + quad * 8];
            o[ct] = __builtin_amdgcn_mfma_f32_16x16x32_bf16(af1, v1, o[ct], 0, 0, 0);
        }
        ol = __builtin_amdgcn_mfma_f32_16x16x32_bf16(af0, ones, ol, 0, 0, 0);
        ol = __builtin_amdgcn_mfma_f32_16x16x32_bf16(af1, ones, ol, 0, 0, 0);
        __builtin_amdgcn_s_setprio(0);
    };

    for (int kt = 0; kt <= qtB; ++kt) {
        __syncthreads();
#pragma unroll
        for (int i = 0; i < 2; ++i) {
            int row = srow0 + i * 32;
            *(bf16x8*)&Ks[row * 72 + scol] = kreg[i];
            *(bf16x8*)&Vs[row * 72 + scol] = vreg[i];
        }
        __syncthreads();

        {
            const int kvn = (kt < qtB ? kt + 1 : kt) * 64;
#pragma unroll
            for (int i = 0; i < 2; ++i) {
                int row = srow0 + i * 32;
                kreg[i] = *(const bf16x8*)&Kg[(size_t)(kvn + row) * DH + scol];
                vreg[i] = *(const bf16x8*)&Vtg[(size_t)row * SEQ + kvn + scol];
            }
        }

        half_step(qfB, oB, olB, kt == qtB);
        if (kt <= qtA)
            half_step(qfA, oA, olA, kt == qtA);
    }

    // epilogue: normalize (v_rcp), write concat[b][s][h*64+d]
#pragma unroll
    for (int ct = 0; ct < 4; ++ct)
#pragma unroll
        for (int r = 0; r < 4; ++r) {
            int rr = wave * 16 + quad * 4 + r;
            int sA = qtA * 64 + rr;
            int sB = qtB * 64 + rr;
            Cat[((size_t)(b * SEQ + sA)) * DM + h * DH + ct * 16 + l15] =
                (__bf16)(oA[ct][r] * fast_rcp(olA[r]));
            Cat[((size_t)(b * SEQ + sB)) * DM + h * DH + ct * 16 + l15] =
                (__bf16)(oB[ct][r] * fast_rcp(olB[r]));
        }
}

// ---------------------------------------------------------------------------
// Kernel 3: output projection, BK=32, async16 staging. XCD locality via
// grid shape only: dim3(8, 64), colTile = blockIdx.x => XCD = colTile —
// each XCD owns exactly one 128-col Wot panel (256 KB, L2-resident).
// ---------------------------------------------------------------------------
__global__ __launch_bounds__(256)
void oproj_kernel(const __bf16* __restrict__ A,
                  const __bf16* __restrict__ Wot,
                  float* __restrict__ C)
{
    const int colTile = blockIdx.x;  // 0..7   (fast dim -> XCD = colTile)
    const int rowTile = blockIdx.y;  // 0..63
    const int r0 = rowTile * 128;
    const int n0 = colTile * 128;

    __shared__ __align__(16) __bf16 As[128 * 32];
    __shared__ __align__(16) __bf16 Bs[128 * 32];

    const int t    = threadIdx.x;
    const int wave = t >> 6;
    const int lane = t & 63;
    const int l15  = lane & 15;
    const int quad = lane >> 4;

    f32x4 acc[2][8];
#pragma unroll
    for (int s = 0; s < 2; ++s)
#pragma unroll
        for (int i = 0; i < 8; ++i) acc[s][i] = (f32x4){0.f, 0.f, 0.f, 0.f};

    const int lrow = lane >> 2;
    const int lcol = (lane & 3) * 8;

    for (int k0 = 0; k0 < DM; k0 += 32) {
        __syncthreads();
#pragma unroll
        for (int c = 0; c < 2; ++c) {
            const int rb = wave * 32 + c * 16;
            async16(&A  [(size_t)(r0 + rb + lrow) * DM + k0 + lcol], &As[rb * 32]);
            async16(&Wot[(size_t)(n0 + rb + lrow) * DM + k0 + lcol], &Bs[rb * 32]);
        }
        __syncthreads();

        bf16x8 a0 = *(const bf16x8*)&As[(wave * 16 + l15) * 32 + quad * 8];
        bf16x8 a1 = *(const bf16x8*)&As[(64 + wave * 16 + l15) * 32 + quad * 8];
#pragma unroll
        for (int ct = 0; ct < 8; ++ct) {
            bf16x8 bb = *(const bf16x8*)&Bs[(ct * 16 + l15) * 32 + quad * 8];
            acc[0][ct] = __builtin_amdgcn_mfma_f32_16x16x32_bf16(a0, bb, acc[0][ct], 0, 0, 0);
            acc[1][ct] = __builtin_amdgcn_mfma_f32_16x16x32_bf16(a1, bb, acc[1][ct], 0, 0, 0);
        }
    }

#pragma unroll
    for (int st = 0; st < 2; ++st)
#pragma unroll
        for (int ct = 0; ct < 8; ++ct)
#pragma unroll
            for (int reg = 0; reg < 4; ++reg) {
                int r = r0 + st * 64 + wave * 16 + quad * 4 + reg;
                int n = n0 + ct * 16 + l15;
                C[(size_t)r * DM + n] = acc[st][ct][reg];
            }
}

// ---------------------------------------------------------------------------
extern "C" void kernel_launch(void* const* d_in, const int* in_sizes, int n_in,
                              void* d_out, int out_size, void* d_ws, size_t ws_size,
                              hipStream_t stream)
{
    (void)in_sizes; (void)n_in; (void)out_size; (void)ws_size;
    const float* X  = (const float*)d_in[0];
    const float* Wq = (const float*)d_in[1];
    const float* Wk = (const float*)d_in[2];
    const float* Wv = (const float*)d_in[3];
    const float* Wo = (const float*)d_in[4];
    float* out = (float*)d_out;

    char* ws = (char*)d_ws;
    const size_t wqkv_b = (size_t)NH * DM * DH * sizeof(__bf16);          // 2 MiB
    const size_t wo_b   = (size_t)DM * DM * sizeof(__bf16);               // 2 MiB
    const size_t big_b  = (size_t)BATCH * NH * SEQ * DH * sizeof(__bf16); // 16 MiB
    __bf16* Wqt = (__bf16*)(ws);                      // Wqt/Wkt/Wvt contiguous = Wcat[3072][1024]
    __bf16* Wkt = (__bf16*)(ws + wqkv_b);
    __bf16* Wvt = (__bf16*)(ws + 2 * wqkv_b);
    __bf16* Wot = (__bf16*)(ws + 3 * wqkv_b);
    __bf16* Qb  = (__bf16*)(ws + 3 * wqkv_b + wo_b);
    __bf16* Kb  = (__bf16*)(ws + 3 * wqkv_b + wo_b + big_b);
    __bf16* Vtb = (__bf16*)(ws + 3 * wqkv_b + wo_b + 2 * big_b);
    __bf16* Cat = (__bf16*)(ws + 3 * wqkv_b + wo_b + 3 * big_b);
    __bf16* Xb  = (__bf16*)(ws + 3 * wqkv_b + wo_b + 4 * big_b);

    prep_kernel<<<dim3(4096 + 768 + 256), 256, 0, stream>>>(
        X, Wq, Wk, Wv, Wo, Xb, Wqt, Wkt, Wvt, Wot);
    qkv_gemm<<<dim3(24, 64), 256, 0, stream>>>(Xb, Wqt, Qb, Kb, Vtb);
    attn_kernel<<<dim3(64, 16), 256, 0, stream>>>(Qb, Kb, Vtb, Cat);
    oproj_kernel<<<dim3(8, 64), 256, 0, stream>>>(Cat, Wot, out);
}

// Round 12
// 260.559 us; speedup vs baseline: 1.0366x; 1.0366x over previous
//
#include <hip/hip_runtime.h>
#include <hip/hip_bf16.h>
#include <math.h>

#define BATCH 4
#define SEQ   2048
#define DM    1024
#define NH    16
#define DH    64

// log2(e) / sqrt(DH)
#define QSCALE 0.1803368801111204f

typedef __bf16 bf16x8 __attribute__((ext_vector_type(8)));
typedef __bf16 bf16x4 __attribute__((ext_vector_type(4)));
typedef float  f32x4  __attribute__((ext_vector_type(4)));

typedef const __attribute__((address_space(1))) unsigned int guint;
typedef __attribute__((address_space(3)))       unsigned int luint;

// async global->LDS, 16 B/lane, wave-uniform LDS base + lane*16
__device__ __forceinline__ void async16(const __bf16* g, __bf16* l) {
    __builtin_amdgcn_global_load_lds((guint*)g, (luint*)l, 16, 0, 0);
}

// raw v_exp_f32 (2^x)
__device__ __forceinline__ float fast_exp2(float x) {
#if __has_builtin(__builtin_amdgcn_exp2f)
    return __builtin_amdgcn_exp2f(x);
#else
    float r; asm("v_exp_f32 %0, %1" : "=v"(r) : "v"(x)); return r;
#endif
}
// raw v_rcp_f32
__device__ __forceinline__ float fast_rcp(float x) {
#if __has_builtin(__builtin_amdgcn_rcpf)
    return __builtin_amdgcn_rcpf(x);
#else
    float r; asm("v_rcp_f32 %0, %1" : "=v"(r) : "v"(x)); return r;
#endif
}

// Load 8 consecutive fp32 elements, convert to bf16x8 (RNE).
__device__ __forceinline__ bf16x8 load8f(const float* __restrict__ base, size_t idx) {
    const float4 a = *(const float4*)(base + idx);
    const float4 b = *(const float4*)(base + idx + 4);
    bf16x8 r;
    r[0] = (__bf16)a.x; r[1] = (__bf16)a.y; r[2] = (__bf16)a.z; r[3] = (__bf16)a.w;
    r[4] = (__bf16)b.x; r[5] = (__bf16)b.y; r[6] = (__bf16)b.z; r[7] = (__bf16)b.w;
    return r;
}

// ---------------------------------------------------------------------------
// Kernel 0: fused prep — xconv (blocks 0..4095), Wq/Wk/Wv transpose
// (blocks 4096..4863), Wo transpose (blocks 4864..5119).
// Wqt/Wkt/Wvt contiguous => Wcat[3072][1024] for qkv_gemm.
// ---------------------------------------------------------------------------
__global__ __launch_bounds__(256)
void prep_kernel(const float* __restrict__ X,
                 const float* __restrict__ Wq,
                 const float* __restrict__ Wk,
                 const float* __restrict__ Wv,
                 const float* __restrict__ Wo,
                 __bf16* __restrict__ Xb,
                 __bf16* __restrict__ Wqt,
                 __bf16* __restrict__ Wkt,
                 __bf16* __restrict__ Wvt,
                 __bf16* __restrict__ Wot)
{
    __shared__ __bf16 T[64][65];
    const int t  = threadIdx.x;
    const int bx = blockIdx.x;

    if (bx < 4096) {                       // ---- xconv: X fp32 -> bf16
        size_t idx = ((size_t)bx * 256 + t) * 8;
        *(bf16x8*)&Xb[idx] = load8f(X, idx);
        return;
    }

    const float* src;
    __bf16* dst;
    int k0, n0, srcN;
    if (bx < 4096 + 768) {                 // ---- Wq/Wk/Wv transpose
        const int i = bx - 4096;
        const int z = i >> 4;              // 0..47
        const int m = z >> 4;              // 0..2
        const int h = z & 15;
        src  = (m == 0 ? Wq : m == 1 ? Wk : Wv) + (size_t)h * DM * DH;
        dst  = (m == 0 ? Wqt : m == 1 ? Wkt : Wvt) + (size_t)h * DH * DM;
        k0   = (i & 15) * 64;
        n0   = 0;
        srcN = DH;
    } else {                               // ---- Wo transpose
        const int i = bx - 4096 - 768;
        src  = Wo;
        dst  = Wot;
        k0   = (i & 15) * 64;
        n0   = (i >> 4) * 64;
        srcN = DM;
    }

#pragma unroll
    for (int i = 0; i < 4; ++i) {
        int row = i * 16 + (t >> 4);
        int col = (t & 15) * 4;
        float4 v = *(const float4*)&src[(size_t)(k0 + row) * srcN + n0 + col];
        T[col + 0][row] = (__bf16)v.x;
        T[col + 1][row] = (__bf16)v.y;
        T[col + 2][row] = (__bf16)v.z;
        T[col + 3][row] = (__bf16)v.w;
    }
    __syncthreads();
#pragma unroll
    for (int i = 0; i < 4; ++i) {
        int n  = i * 16 + (t >> 4);
        int kc = (t & 15) * 4;
        bf16x4 v;
        v[0] = T[n][kc + 0]; v[1] = T[n][kc + 1];
        v[2] = T[n][kc + 2]; v[3] = T[n][kc + 3];
        *(bf16x4*)&dst[(size_t)(n0 + n) * DM + k0 + kc] = v;
    }
}

// ---------------------------------------------------------------------------
// Kernel 1: QKV projection as ONE GEMM  C[8192][3072] = Xb · Wcat^T.
// Exact R9 form: grid (64,24) rowTile-fast, 128x128, BK=32, async16
// staging, LDS-bounce coalesced Q/K epilogue. (R11 proved colTile-fast
// regresses: the big streaming operand must not be replicated per-XCD.)
// ---------------------------------------------------------------------------
__global__ __launch_bounds__(256)
void qkv_gemm(const __bf16* __restrict__ Xb,
              const __bf16* __restrict__ Wcat,
              __bf16* __restrict__ Qo,
              __bf16* __restrict__ Ko,
              __bf16* __restrict__ Vto)
{
    const int rowTile = blockIdx.x;  // 0..63
    const int colTile = blockIdx.y;  // 0..23
    const int r0 = rowTile * 128;
    const int n0 = colTile * 128;

    __shared__ __align__(16) __bf16 SM[8192];   // As = SM[0..4095], Bs = SM[4096..8191]
    __bf16* As = SM;
    __bf16* Bs = SM + 4096;

    const int t    = threadIdx.x;
    const int wave = t >> 6;
    const int lane = t & 63;
    const int l15  = lane & 15;
    const int quad = lane >> 4;

    f32x4 acc[2][8];
#pragma unroll
    for (int s = 0; s < 2; ++s)
#pragma unroll
        for (int i = 0; i < 8; ++i) acc[s][i] = (f32x4){0.f, 0.f, 0.f, 0.f};

    const int lrow = lane >> 2;
    const int lcol = (lane & 3) * 8;

    for (int k0 = 0; k0 < DM; k0 += 32) {
        __syncthreads();
#pragma unroll
        for (int c = 0; c < 2; ++c) {
            const int rb = wave * 32 + c * 16;
            async16(&Xb  [(size_t)(r0 + rb + lrow) * DM + k0 + lcol], &As[rb * 32]);
            async16(&Wcat[(size_t)(n0 + rb + lrow) * DM + k0 + lcol], &Bs[rb * 32]);
        }
        __syncthreads();

        bf16x8 a0 = *(const bf16x8*)&As[(wave * 16 + l15) * 32 + quad * 8];
        bf16x8 a1 = *(const bf16x8*)&As[(64 + wave * 16 + l15) * 32 + quad * 8];
#pragma unroll
        for (int ct = 0; ct < 8; ++ct) {
            bf16x8 bb = *(const bf16x8*)&Bs[(ct * 16 + l15) * 32 + quad * 8];
            acc[0][ct] = __builtin_amdgcn_mfma_f32_16x16x32_bf16(a0, bb, acc[0][ct], 0, 0, 0);
            acc[1][ct] = __builtin_amdgcn_mfma_f32_16x16x32_bf16(a1, bb, acc[1][ct], 0, 0, 0);
        }
    }

    // ---- epilogue: block-uniform dispatch on destination matrix
    const int mat = colTile >> 3;   // 0=Q, 1=K, 2=V
    if (mat < 2) {
        __bf16* __restrict__ Dst = (mat == 0) ? Qo : Ko;
        const float scale = (mat == 0) ? QSCALE : 1.0f;
        __syncthreads();                          // all waves done reading As/Bs
        char* slab = (char*)SM + wave * 4096;     // wave-private [16][128] bf16 tile
        const int nb = n0 & 1023;                 // column base within the matrix
#pragma unroll
        for (int st = 0; st < 2; ++st) {
            // scatter acc into swizzled slab (scalar LDS writes)
#pragma unroll
            for (int ct = 0; ct < 8; ++ct)
#pragma unroll
                for (int reg = 0; reg < 4; ++reg) {
                    const int row = quad * 4 + reg;
                    *(__bf16*)(slab + row * 256 +
                               (((ct * 16 + l15) * 2) ^ ((row & 7) << 4))) =
                        (__bf16)(acc[st][ct][reg] * scale);
                }
            // read back row-major (wave-private: DS ops in-order) and store
            // coalesced 16 B/lane
#pragma unroll
            for (int i = 0; i < 4; ++i) {
                const int row = i * 4 + quad;
                bf16x8 w = *(const bf16x8*)(slab + row * 256 +
                                            ((l15 * 16) ^ ((row & 7) << 4)));
                const int rg = r0 + st * 64 + wave * 16 + row;
                const int b  = rg >> 11;
                const int s  = rg & (SEQ - 1);
                const int nn = nb + l15 * 8;
                const int h  = nn >> 6;
                const int d  = nn & 63;
                *(bf16x8*)&Dst[(((size_t)(b * NH + h)) * SEQ + s) * DH + d] = w;
            }
        }
    } else {
#pragma unroll
        for (int st = 0; st < 2; ++st) {
            const int r = r0 + st * 64 + wave * 16 + quad * 4;
            const int b = r >> 11;
            const int s = r & (SEQ - 1);
#pragma unroll
            for (int ct = 0; ct < 8; ++ct) {
                const int n = (n0 + ct * 16 + l15) & 1023;
                const int h = n >> 6;
                const int d = n & 63;
                bf16x4 vv;
                vv[0] = (__bf16)acc[st][ct][0]; vv[1] = (__bf16)acc[st][ct][1];
                vv[2] = (__bf16)acc[st][ct][2]; vv[3] = (__bf16)acc[st][ct][3];
                *(bf16x4*)&Vto[(((size_t)(b * NH + h)) * DH + d) * SEQ + s] = vv;
            }
        }
    }
}

// ---------------------------------------------------------------------------
// Kernel 2: causal flash attention — EXACT R9 kernel (79.0 µs, FETCH 37 MB,
// proven). Grid (bh=64, x=16): XCD = bh%8 colocates all 16 blocks of a bh
// so the 512 KB K/V panel stays in one L2 (FETCH 131 -> 37 MB, -8.4 µs).
// ---------------------------------------------------------------------------
__global__ __launch_bounds__(256)
void attn_kernel(const __bf16* __restrict__ Q,
                 const __bf16* __restrict__ K,
                 const __bf16* __restrict__ Vt,
                 __bf16* __restrict__ Cat)
{
    const int bh  = blockIdx.x;       // 0..63  (fast dim -> XCD = bh%8)
    const int x   = blockIdx.y;       // 0..15
    const int qtA = x;                // light tile
    const int qtB = 31 - x;           // heavy tile
    const int b   = bh >> 4;
    const int h   = bh & 15;

    const __bf16* Qg  = Q  + (size_t)bh * SEQ * DH;
    const __bf16* Kg  = K  + (size_t)bh * SEQ * DH;
    const __bf16* Vtg = Vt + (size_t)bh * DH * SEQ;

    __shared__ __align__(16) __bf16 Ks[64 * 72];
    __shared__ __align__(16) __bf16 Vs[64 * 72];
    __shared__ __align__(16) __bf16 Ps[64 * 72];

    const int t    = threadIdx.x;
    const int wave = t >> 6;
    const int lane = t & 63;
    const int l15  = lane & 15;
    const int quad = lane >> 4;

    bf16x8 qfA[2], qfB[2];
    {
        const size_t rA = (size_t)(qtA * 64 + wave * 16 + l15);
        qfA[0] = *(const bf16x8*)&Qg[rA * DH + quad * 8];
        qfA[1] = *(const bf16x8*)&Qg[rA * DH + 32 + quad * 8];
        const size_t rB = (size_t)(qtB * 64 + wave * 16 + l15);
        qfB[0] = *(const bf16x8*)&Qg[rB * DH + quad * 8];
        qfB[1] = *(const bf16x8*)&Qg[rB * DH + 32 + quad * 8];
    }

    bf16x8 ones;
#pragma unroll
    for (int j = 0; j < 8; ++j) ones[j] = (__bf16)1.0f;

    f32x4 oA[4], oB[4], olA, olB;
#pragma unroll
    for (int ct = 0; ct < 4; ++ct) {
        oA[ct] = (f32x4){0.f, 0.f, 0.f, 0.f};
        oB[ct] = (f32x4){0.f, 0.f, 0.f, 0.f};
    }
    olA = (f32x4){0.f, 0.f, 0.f, 0.f};
    olB = (f32x4){0.f, 0.f, 0.f, 0.f};

    const int srow0 = t >> 3;
    const int scol  = (t & 7) * 8;
    bf16x8 kreg[2], vreg[2];
#pragma unroll
    for (int i = 0; i < 2; ++i) {
        int row = srow0 + i * 32;
        kreg[i] = *(const bf16x8*)&Kg[(size_t)row * DH + scol];
        vreg[i] = *(const bf16x8*)&Vtg[(size_t)row * SEQ + scol];
    }

    auto half_step = [&](const bf16x8* qf, f32x4* o, f32x4& ol, bool diag) {
        f32x4 sc[4];
        __builtin_amdgcn_s_setprio(1);
#pragma unroll
        for (int ct = 0; ct < 4; ++ct) {
            sc[ct] = (f32x4){0.f, 0.f, 0.f, 0.f};
            bf16x8 b0 = *(const bf16x8*)&Ks[(ct * 16 + l15) * 72 + quad * 8];
            sc[ct] = __builtin_amdgcn_mfma_f32_16x16x32_bf16(qf[0], b0, sc[ct], 0, 0, 0);
            bf16x8 b1 = *(const bf16x8*)&Ks[(ct * 16 + l15) * 72 + 32 + quad * 8];
            sc[ct] = __builtin_amdgcn_mfma_f32_16x16x32_bf16(qf[1], b1, sc[ct], 0, 0, 0);
        }
        __builtin_amdgcn_s_setprio(0);
        if (diag) {
#pragma unroll
            for (int ct = 0; ct < 4; ++ct)
#pragma unroll
                for (int r = 0; r < 4; ++r) {
                    int qr = wave * 16 + quad * 4 + r;
                    int kc = ct * 16 + l15;
                    if (kc > qr) sc[ct][r] = -INFINITY;
                }
        }
#pragma unroll
        for (int ct = 0; ct < 4; ++ct)
#pragma unroll
            for (int r = 0; r < 4; ++r)
                sc[ct][r] = fast_exp2(sc[ct][r]);

#pragma unroll
        for (int ct = 0; ct < 4; ++ct)
#pragma unroll
            for (int r = 0; r < 4; ++r)
                Ps[(wave * 16 + quad * 4 + r) * 72 + ct * 16 + l15] =
                    (__bf16)sc[ct][r];

        bf16x8 af0 = *(const bf16x8*)&Ps[(wave * 16 + l15) * 72 + quad * 8];
        bf16x8 af1 = *(const bf16x8*)&Ps[(wave * 16 + l15) * 72 + 32 + quad * 8];

        __builtin_amdgcn_s_setprio(1);
#pragma unroll
        for (int ct = 0; ct < 4; ++ct) {
            bf16x8 v0 = *(const bf16x8*)&Vs[(ct * 16 + l15) * 72 + quad * 8];
            o[ct] = __builtin_amdgcn_mfma_f32_16x16x32_bf16(af0, v0, o[ct], 0, 0, 0);
            bf16x8 v1 = *(const bf16x8*)&Vs[(ct * 16 + l15) * 72 + 32 + quad * 8];
            o[ct] = __builtin_amdgcn_mfma_f32_16x16x32_bf16(af1, v1, o[ct], 0, 0, 0);
        }
        ol = __builtin_amdgcn_mfma_f32_16x16x32_bf16(af0, ones, ol, 0, 0, 0);
        ol = __builtin_amdgcn_mfma_f32_16x16x32_bf16(af1, ones, ol, 0, 0, 0);
        __builtin_amdgcn_s_setprio(0);
    };

    for (int kt = 0; kt <= qtB; ++kt) {
        __syncthreads();
#pragma unroll
        for (int i = 0; i < 2; ++i) {
            int row = srow0 + i * 32;
            *(bf16x8*)&Ks[row * 72 + scol] = kreg[i];
            *(bf16x8*)&Vs[row * 72 + scol] = vreg[i];
        }
        __syncthreads();

        {
            const int kvn = (kt < qtB ? kt + 1 : kt) * 64;
#pragma unroll
            for (int i = 0; i < 2; ++i) {
                int row = srow0 + i * 32;
                kreg[i] = *(const bf16x8*)&Kg[(size_t)(kvn + row) * DH + scol];
                vreg[i] = *(const bf16x8*)&Vtg[(size_t)row * SEQ + kvn + scol];
            }
        }

        half_step(qfB, oB, olB, kt == qtB);
        if (kt <= qtA)
            half_step(qfA, oA, olA, kt == qtA);
    }

    // epilogue: normalize (v_rcp), write concat[b][s][h*64+d]
#pragma unroll
    for (int ct = 0; ct < 4; ++ct)
#pragma unroll
        for (int r = 0; r < 4; ++r) {
            int rr = wave * 16 + quad * 4 + r;
            int sA = qtA * 64 + rr;
            int sB = qtB * 64 + rr;
            Cat[((size_t)(b * SEQ + sA)) * DM + h * DH + ct * 16 + l15] =
                (__bf16)(oA[ct][r] * fast_rcp(olA[r]));
            Cat[((size_t)(b * SEQ + sB)) * DM + h * DH + ct * 16 + l15] =
                (__bf16)(oB[ct][r] * fast_rcp(olB[r]));
        }
}

// ---------------------------------------------------------------------------
// Kernel 3: output projection — exact R9 form: grid (64,8) rowTile-fast,
// BK=32, async16 staging.
// ---------------------------------------------------------------------------
__global__ __launch_bounds__(256)
void oproj_kernel(const __bf16* __restrict__ A,
                  const __bf16* __restrict__ Wot,
                  float* __restrict__ C)
{
    const int rowTile = blockIdx.x;  // 0..63
    const int colTile = blockIdx.y;  // 0..7
    const int r0 = rowTile * 128;
    const int n0 = colTile * 128;

    __shared__ __align__(16) __bf16 As[128 * 32];
    __shared__ __align__(16) __bf16 Bs[128 * 32];

    const int t    = threadIdx.x;
    const int wave = t >> 6;
    const int lane = t & 63;
    const int l15  = lane & 15;
    const int quad = lane >> 4;

    f32x4 acc[2][8];
#pragma unroll
    for (int s = 0; s < 2; ++s)
#pragma unroll
        for (int i = 0; i < 8; ++i) acc[s][i] = (f32x4){0.f, 0.f, 0.f, 0.f};

    const int lrow = lane >> 2;
    const int lcol = (lane & 3) * 8;

    for (int k0 = 0; k0 < DM; k0 += 32) {
        __syncthreads();
#pragma unroll
        for (int c = 0; c < 2; ++c) {
            const int rb = wave * 32 + c * 16;
            async16(&A  [(size_t)(r0 + rb + lrow) * DM + k0 + lcol], &As[rb * 32]);
            async16(&Wot[(size_t)(n0 + rb + lrow) * DM + k0 + lcol], &Bs[rb * 32]);
        }
        __syncthreads();

        bf16x8 a0 = *(const bf16x8*)&As[(wave * 16 + l15) * 32 + quad * 8];
        bf16x8 a1 = *(const bf16x8*)&As[(64 + wave * 16 + l15) * 32 + quad * 8];
#pragma unroll
        for (int ct = 0; ct < 8; ++ct) {
            bf16x8 bb = *(const bf16x8*)&Bs[(ct * 16 + l15) * 32 + quad * 8];
            acc[0][ct] = __builtin_amdgcn_mfma_f32_16x16x32_bf16(a0, bb, acc[0][ct], 0, 0, 0);
            acc[1][ct] = __builtin_amdgcn_mfma_f32_16x16x32_bf16(a1, bb, acc[1][ct], 0, 0, 0);
        }
    }

#pragma unroll
    for (int st = 0; st < 2; ++st)
#pragma unroll
        for (int ct = 0; ct < 8; ++ct)
#pragma unroll
            for (int reg = 0; reg < 4; ++reg) {
                int r = r0 + st * 64 + wave * 16 + quad * 4 + reg;
                int n = n0 + ct * 16 + l15;
                C[(size_t)r * DM + n] = acc[st][ct][reg];
            }
}

// ---------------------------------------------------------------------------
extern "C" void kernel_launch(void* const* d_in, const int* in_sizes, int n_in,
                              void* d_out, int out_size, void* d_ws, size_t ws_size,
                              hipStream_t stream)
{
    (void)in_sizes; (void)n_in; (void)out_size; (void)ws_size;
    const float* X  = (const float*)d_in[0];
    const float* Wq = (const float*)d_in[1];
    const float* Wk = (const float*)d_in[2];
    const float* Wv = (const float*)d_in[3];
    const float* Wo = (const float*)d_in[4];
    float* out = (float*)d_out;

    char* ws = (char*)d_ws;
    const size_t wqkv_b = (size_t)NH * DM * DH * sizeof(__bf16);          // 2 MiB
    const size_t wo_b   = (size_t)DM * DM * sizeof(__bf16);               // 2 MiB
    const size_t big_b  = (size_t)BATCH * NH * SEQ * DH * sizeof(__bf16); // 16 MiB
    __bf16* Wqt = (__bf16*)(ws);                      // Wqt/Wkt/Wvt contiguous = Wcat[3072][1024]
    __bf16* Wkt = (__bf16*)(ws + wqkv_b);
    __bf16* Wvt = (__bf16*)(ws + 2 * wqkv_b);
    __bf16* Wot = (__bf16*)(ws + 3 * wqkv_b);
    __bf16* Qb  = (__bf16*)(ws + 3 * wqkv_b + wo_b);
    __bf16* Kb  = (__bf16*)(ws + 3 * wqkv_b + wo_b + big_b);
    __bf16* Vtb = (__bf16*)(ws + 3 * wqkv_b + wo_b + 2 * big_b);
    __bf16* Cat = (__bf16*)(ws + 3 * wqkv_b + wo_b + 3 * big_b);
    __bf16* Xb  = (__bf16*)(ws + 3 * wqkv_b + wo_b + 4 * big_b);

    prep_kernel<<<dim3(4096 + 768 + 256), 256, 0, stream>>>(
        X, Wq, Wk, Wv, Wo, Xb, Wqt, Wkt, Wvt, Wot);
    qkv_gemm<<<dim3(64, 24), 256, 0, stream>>>(Xb, Wqt, Qb, Kb, Vtb);
    attn_kernel<<<dim3(64, 16), 256, 0, stream>>>(Qb, Kb, Vtb, Cat);
    oproj_kernel<<<dim3(64, 8), 256, 0, stream>>>(Cat, Wot, out);
}

// Round 13
// 256.504 us; speedup vs baseline: 1.0530x; 1.0158x over previous
//
#include <hip/hip_runtime.h>
#include <hip/hip_bf16.h>
#include <math.h>

#define BATCH 4
#define SEQ   2048
#define DM    1024
#define NH    16
#define DH    64

// log2(e) / sqrt(DH)
#define QSCALE 0.1803368801111204f

typedef __bf16 bf16x8 __attribute__((ext_vector_type(8)));
typedef __bf16 bf16x4 __attribute__((ext_vector_type(4)));
typedef float  f32x4  __attribute__((ext_vector_type(4)));

typedef const __attribute__((address_space(1))) unsigned int guint;
typedef __attribute__((address_space(3)))       unsigned int luint;

// async global->LDS, 16 B/lane, wave-uniform LDS base + lane*16
__device__ __forceinline__ void async16(const __bf16* g, __bf16* l) {
    __builtin_amdgcn_global_load_lds((guint*)g, (luint*)l, 16, 0, 0);
}

// raw v_exp_f32 (2^x)
__device__ __forceinline__ float fast_exp2(float x) {
#if __has_builtin(__builtin_amdgcn_exp2f)
    return __builtin_amdgcn_exp2f(x);
#else
    float r; asm("v_exp_f32 %0, %1" : "=v"(r) : "v"(x)); return r;
#endif
}
// raw v_rcp_f32
__device__ __forceinline__ float fast_rcp(float x) {
#if __has_builtin(__builtin_amdgcn_rcpf)
    return __builtin_amdgcn_rcpf(x);
#else
    float r; asm("v_rcp_f32 %0, %1" : "=v"(r) : "v"(x)); return r;
#endif
}

// Load 8 consecutive fp32 elements, convert to bf16x8 (RNE).
__device__ __forceinline__ bf16x8 load8f(const float* __restrict__ base, size_t idx) {
    const float4 a = *(const float4*)(base + idx);
    const float4 b = *(const float4*)(base + idx + 4);
    bf16x8 r;
    r[0] = (__bf16)a.x; r[1] = (__bf16)a.y; r[2] = (__bf16)a.z; r[3] = (__bf16)a.w;
    r[4] = (__bf16)b.x; r[5] = (__bf16)b.y; r[6] = (__bf16)b.z; r[7] = (__bf16)b.w;
    return r;
}

// ---------------------------------------------------------------------------
// Kernel 0: fused prep — xconv (blocks 0..4095), Wq/Wk/Wv transpose
// (blocks 4096..4863), Wo transpose (blocks 4864..5119).
// Wqt/Wkt/Wvt contiguous => Wcat[3072][1024] for qkv_gemm.
// (unchanged — control)
// ---------------------------------------------------------------------------
__global__ __launch_bounds__(256)
void prep_kernel(const float* __restrict__ X,
                 const float* __restrict__ Wq,
                 const float* __restrict__ Wk,
                 const float* __restrict__ Wv,
                 const float* __restrict__ Wo,
                 __bf16* __restrict__ Xb,
                 __bf16* __restrict__ Wqt,
                 __bf16* __restrict__ Wkt,
                 __bf16* __restrict__ Wvt,
                 __bf16* __restrict__ Wot)
{
    __shared__ __bf16 T[64][65];
    const int t  = threadIdx.x;
    const int bx = blockIdx.x;

    if (bx < 4096) {                       // ---- xconv: X fp32 -> bf16
        size_t idx = ((size_t)bx * 256 + t) * 8;
        *(bf16x8*)&Xb[idx] = load8f(X, idx);
        return;
    }

    const float* src;
    __bf16* dst;
    int k0, n0, srcN;
    if (bx < 4096 + 768) {                 // ---- Wq/Wk/Wv transpose
        const int i = bx - 4096;
        const int z = i >> 4;              // 0..47
        const int m = z >> 4;              // 0..2
        const int h = z & 15;
        src  = (m == 0 ? Wq : m == 1 ? Wk : Wv) + (size_t)h * DM * DH;
        dst  = (m == 0 ? Wqt : m == 1 ? Wkt : Wvt) + (size_t)h * DH * DM;
        k0   = (i & 15) * 64;
        n0   = 0;
        srcN = DH;
    } else {                               // ---- Wo transpose
        const int i = bx - 4096 - 768;
        src  = Wo;
        dst  = Wot;
        k0   = (i & 15) * 64;
        n0   = (i >> 4) * 64;
        srcN = DM;
    }

#pragma unroll
    for (int i = 0; i < 4; ++i) {
        int row = i * 16 + (t >> 4);
        int col = (t & 15) * 4;
        float4 v = *(const float4*)&src[(size_t)(k0 + row) * srcN + n0 + col];
        T[col + 0][row] = (__bf16)v.x;
        T[col + 1][row] = (__bf16)v.y;
        T[col + 2][row] = (__bf16)v.z;
        T[col + 3][row] = (__bf16)v.w;
    }
    __syncthreads();
#pragma unroll
    for (int i = 0; i < 4; ++i) {
        int n  = i * 16 + (t >> 4);
        int kc = (t & 15) * 4;
        bf16x4 v;
        v[0] = T[n][kc + 0]; v[1] = T[n][kc + 1];
        v[2] = T[n][kc + 2]; v[3] = T[n][kc + 3];
        *(bf16x4*)&dst[(size_t)(n0 + n) * DM + k0 + kc] = v;
    }
}

// ---------------------------------------------------------------------------
// Kernel 1: QKV projection as ONE GEMM  C[8192][3072] = Xb · Wcat^T.
// Exact R9/R12 form: grid (64,24) rowTile-fast, 128x128, BK=32, async16
// staging, LDS-bounce coalesced Q/K epilogue. (unchanged — control)
// ---------------------------------------------------------------------------
__global__ __launch_bounds__(256)
void qkv_gemm(const __bf16* __restrict__ Xb,
              const __bf16* __restrict__ Wcat,
              __bf16* __restrict__ Qo,
              __bf16* __restrict__ Ko,
              __bf16* __restrict__ Vto)
{
    const int rowTile = blockIdx.x;  // 0..63
    const int colTile = blockIdx.y;  // 0..23
    const int r0 = rowTile * 128;
    const int n0 = colTile * 128;

    __shared__ __align__(16) __bf16 SM[8192];   // As = SM[0..4095], Bs = SM[4096..8191]
    __bf16* As = SM;
    __bf16* Bs = SM + 4096;

    const int t    = threadIdx.x;
    const int wave = t >> 6;
    const int lane = t & 63;
    const int l15  = lane & 15;
    const int quad = lane >> 4;

    f32x4 acc[2][8];
#pragma unroll
    for (int s = 0; s < 2; ++s)
#pragma unroll
        for (int i = 0; i < 8; ++i) acc[s][i] = (f32x4){0.f, 0.f, 0.f, 0.f};

    const int lrow = lane >> 2;
    const int lcol = (lane & 3) * 8;

    for (int k0 = 0; k0 < DM; k0 += 32) {
        __syncthreads();
#pragma unroll
        for (int c = 0; c < 2; ++c) {
            const int rb = wave * 32 + c * 16;
            async16(&Xb  [(size_t)(r0 + rb + lrow) * DM + k0 + lcol], &As[rb * 32]);
            async16(&Wcat[(size_t)(n0 + rb + lrow) * DM + k0 + lcol], &Bs[rb * 32]);
        }
        __syncthreads();

        bf16x8 a0 = *(const bf16x8*)&As[(wave * 16 + l15) * 32 + quad * 8];
        bf16x8 a1 = *(const bf16x8*)&As[(64 + wave * 16 + l15) * 32 + quad * 8];
#pragma unroll
        for (int ct = 0; ct < 8; ++ct) {
            bf16x8 bb = *(const bf16x8*)&Bs[(ct * 16 + l15) * 32 + quad * 8];
            acc[0][ct] = __builtin_amdgcn_mfma_f32_16x16x32_bf16(a0, bb, acc[0][ct], 0, 0, 0);
            acc[1][ct] = __builtin_amdgcn_mfma_f32_16x16x32_bf16(a1, bb, acc[1][ct], 0, 0, 0);
        }
    }

    // ---- epilogue: block-uniform dispatch on destination matrix
    const int mat = colTile >> 3;   // 0=Q, 1=K, 2=V
    if (mat < 2) {
        __bf16* __restrict__ Dst = (mat == 0) ? Qo : Ko;
        const float scale = (mat == 0) ? QSCALE : 1.0f;
        __syncthreads();                          // all waves done reading As/Bs
        char* slab = (char*)SM + wave * 4096;     // wave-private [16][128] bf16 tile
        const int nb = n0 & 1023;                 // column base within the matrix
#pragma unroll
        for (int st = 0; st < 2; ++st) {
            // scatter acc into swizzled slab (scalar LDS writes)
#pragma unroll
            for (int ct = 0; ct < 8; ++ct)
#pragma unroll
                for (int reg = 0; reg < 4; ++reg) {
                    const int row = quad * 4 + reg;
                    *(__bf16*)(slab + row * 256 +
                               (((ct * 16 + l15) * 2) ^ ((row & 7) << 4))) =
                        (__bf16)(acc[st][ct][reg] * scale);
                }
            // read back row-major (wave-private: DS ops in-order) and store
            // coalesced 16 B/lane
#pragma unroll
            for (int i = 0; i < 4; ++i) {
                const int row = i * 4 + quad;
                bf16x8 w = *(const bf16x8*)(slab + row * 256 +
                                            ((l15 * 16) ^ ((row & 7) << 4)));
                const int rg = r0 + st * 64 + wave * 16 + row;
                const int b  = rg >> 11;
                const int s  = rg & (SEQ - 1);
                const int nn = nb + l15 * 8;
                const int h  = nn >> 6;
                const int d  = nn & 63;
                *(bf16x8*)&Dst[(((size_t)(b * NH + h)) * SEQ + s) * DH + d] = w;
            }
        }
    } else {
#pragma unroll
        for (int st = 0; st < 2; ++st) {
            const int r = r0 + st * 64 + wave * 16 + quad * 4;
            const int b = r >> 11;
            const int s = r & (SEQ - 1);
#pragma unroll
            for (int ct = 0; ct < 8; ++ct) {
                const int n = (n0 + ct * 16 + l15) & 1023;
                const int h = n >> 6;
                const int d = n & 63;
                bf16x4 vv;
                vv[0] = (__bf16)acc[st][ct][0]; vv[1] = (__bf16)acc[st][ct][1];
                vv[2] = (__bf16)acc[st][ct][2]; vv[3] = (__bf16)acc[st][ct][3];
                *(bf16x4*)&Vto[(((size_t)(b * NH + h)) * DH + d) * SEQ + s] = vv;
            }
        }
    }
}

// ---------------------------------------------------------------------------
// Kernel 2: causal flash attention — R9 base (grid (bh,x): XCD = bh%8,
// FETCH 37 MB) + MERGED both-active fast path: for kt <= qtA, the two
// tiles' half-steps run as one pass — Ks/Vs fragments loaded ONCE feed
// both tiles' MFMAs, and B's serial softmax VALU chain overlaps A's
// independent QK MFMAs (separate pipes). Per-accumulator MFMA chains keep
// identical operands in identical kt order => bit-identical output.
// B's diagonal can't occur in the merged path (kt <= qtA < qtB always).
// Ps grows to [128][72] (B rows 0..63, A rows 64..127): LDS 36.9 KB ->
// 4 blocks/CU, exactly the grid's 4-blocks/CU residency.
// ---------------------------------------------------------------------------
__global__ __launch_bounds__(256)
void attn_kernel(const __bf16* __restrict__ Q,
                 const __bf16* __restrict__ K,
                 const __bf16* __restrict__ Vt,
                 __bf16* __restrict__ Cat)
{
    const int bh  = blockIdx.x;       // 0..63  (fast dim -> XCD = bh%8)
    const int x   = blockIdx.y;       // 0..15
    const int qtA = x;                // light tile
    const int qtB = 31 - x;           // heavy tile
    const int b   = bh >> 4;
    const int h   = bh & 15;

    const __bf16* Qg  = Q  + (size_t)bh * SEQ * DH;
    const __bf16* Kg  = K  + (size_t)bh * SEQ * DH;
    const __bf16* Vtg = Vt + (size_t)bh * DH * SEQ;

    __shared__ __align__(16) __bf16 Ks[64 * 72];
    __shared__ __align__(16) __bf16 Vs[64 * 72];
    __shared__ __align__(16) __bf16 Ps[128 * 72];  // rows 0..63 B, 64..127 A

    const int t    = threadIdx.x;
    const int wave = t >> 6;
    const int lane = t & 63;
    const int l15  = lane & 15;
    const int quad = lane >> 4;

    bf16x8 qfA[2], qfB[2];
    {
        const size_t rA = (size_t)(qtA * 64 + wave * 16 + l15);
        qfA[0] = *(const bf16x8*)&Qg[rA * DH + quad * 8];
        qfA[1] = *(const bf16x8*)&Qg[rA * DH + 32 + quad * 8];
        const size_t rB = (size_t)(qtB * 64 + wave * 16 + l15);
        qfB[0] = *(const bf16x8*)&Qg[rB * DH + quad * 8];
        qfB[1] = *(const bf16x8*)&Qg[rB * DH + 32 + quad * 8];
    }

    bf16x8 ones;
#pragma unroll
    for (int j = 0; j < 8; ++j) ones[j] = (__bf16)1.0f;

    f32x4 oA[4], oB[4], olA, olB;
#pragma unroll
    for (int ct = 0; ct < 4; ++ct) {
        oA[ct] = (f32x4){0.f, 0.f, 0.f, 0.f};
        oB[ct] = (f32x4){0.f, 0.f, 0.f, 0.f};
    }
    olA = (f32x4){0.f, 0.f, 0.f, 0.f};
    olB = (f32x4){0.f, 0.f, 0.f, 0.f};

    const int srow0 = t >> 3;
    const int scol  = (t & 7) * 8;
    bf16x8 kreg[2], vreg[2];
#pragma unroll
    for (int i = 0; i < 2; ++i) {
        int row = srow0 + i * 32;
        kreg[i] = *(const bf16x8*)&Kg[(size_t)row * DH + scol];
        vreg[i] = *(const bf16x8*)&Vtg[(size_t)row * SEQ + scol];
    }

    // B-only half-step (identical to R1/R9 path)
    auto half_stepB = [&](bool diag) {
        f32x4 sc[4];
        __builtin_amdgcn_s_setprio(1);
#pragma unroll
        for (int ct = 0; ct < 4; ++ct) {
            sc[ct] = (f32x4){0.f, 0.f, 0.f, 0.f};
            bf16x8 b0 = *(const bf16x8*)&Ks[(ct * 16 + l15) * 72 + quad * 8];
            sc[ct] = __builtin_amdgcn_mfma_f32_16x16x32_bf16(qfB[0], b0, sc[ct], 0, 0, 0);
            bf16x8 b1 = *(const bf16x8*)&Ks[(ct * 16 + l15) * 72 + 32 + quad * 8];
            sc[ct] = __builtin_amdgcn_mfma_f32_16x16x32_bf16(qfB[1], b1, sc[ct], 0, 0, 0);
        }
        __builtin_amdgcn_s_setprio(0);
        if (diag) {
#pragma unroll
            for (int ct = 0; ct < 4; ++ct)
#pragma unroll
                for (int r = 0; r < 4; ++r) {
                    int qr = wave * 16 + quad * 4 + r;
                    int kc = ct * 16 + l15;
                    if (kc > qr) sc[ct][r] = -INFINITY;
                }
        }
#pragma unroll
        for (int ct = 0; ct < 4; ++ct)
#pragma unroll
            for (int r = 0; r < 4; ++r)
                sc[ct][r] = fast_exp2(sc[ct][r]);

#pragma unroll
        for (int ct = 0; ct < 4; ++ct)
#pragma unroll
            for (int r = 0; r < 4; ++r)
                Ps[(wave * 16 + quad * 4 + r) * 72 + ct * 16 + l15] =
                    (__bf16)sc[ct][r];

        bf16x8 af0 = *(const bf16x8*)&Ps[(wave * 16 + l15) * 72 + quad * 8];
        bf16x8 af1 = *(const bf16x8*)&Ps[(wave * 16 + l15) * 72 + 32 + quad * 8];

        __builtin_amdgcn_s_setprio(1);
#pragma unroll
        for (int ct = 0; ct < 4; ++ct) {
            bf16x8 v0 = *(const bf16x8*)&Vs[(ct * 16 + l15) * 72 + quad * 8];
            oB[ct] = __builtin_amdgcn_mfma_f32_16x16x32_bf16(af0, v0, oB[ct], 0, 0, 0);
            bf16x8 v1 = *(const bf16x8*)&Vs[(ct * 16 + l15) * 72 + 32 + quad * 8];
            oB[ct] = __builtin_amdgcn_mfma_f32_16x16x32_bf16(af1, v1, oB[ct], 0, 0, 0);
        }
        olB = __builtin_amdgcn_mfma_f32_16x16x32_bf16(af0, ones, olB, 0, 0, 0);
        olB = __builtin_amdgcn_mfma_f32_16x16x32_bf16(af1, ones, olB, 0, 0, 0);
        __builtin_amdgcn_s_setprio(0);
    };

    // merged both-active step: shared Ks/Vs fragments, interleaved chains
    auto merged_step = [&](bool diagA) {
        f32x4 scB[4], scA[4];
        __builtin_amdgcn_s_setprio(1);
#pragma unroll
        for (int ct = 0; ct < 4; ++ct) {
            bf16x8 b0 = *(const bf16x8*)&Ks[(ct * 16 + l15) * 72 + quad * 8];
            bf16x8 b1 = *(const bf16x8*)&Ks[(ct * 16 + l15) * 72 + 32 + quad * 8];
            scB[ct] = (f32x4){0.f, 0.f, 0.f, 0.f};
            scB[ct] = __builtin_amdgcn_mfma_f32_16x16x32_bf16(qfB[0], b0, scB[ct], 0, 0, 0);
            scB[ct] = __builtin_amdgcn_mfma_f32_16x16x32_bf16(qfB[1], b1, scB[ct], 0, 0, 0);
            scA[ct] = (f32x4){0.f, 0.f, 0.f, 0.f};
            scA[ct] = __builtin_amdgcn_mfma_f32_16x16x32_bf16(qfA[0], b0, scA[ct], 0, 0, 0);
            scA[ct] = __builtin_amdgcn_mfma_f32_16x16x32_bf16(qfA[1], b1, scA[ct], 0, 0, 0);
        }
        __builtin_amdgcn_s_setprio(0);

        if (diagA) {
#pragma unroll
            for (int ct = 0; ct < 4; ++ct)
#pragma unroll
                for (int r = 0; r < 4; ++r) {
                    int qr = wave * 16 + quad * 4 + r;
                    int kc = ct * 16 + l15;
                    if (kc > qr) scA[ct][r] = -INFINITY;
                }
        }
#pragma unroll
        for (int ct = 0; ct < 4; ++ct)
#pragma unroll
            for (int r = 0; r < 4; ++r) {
                scB[ct][r] = fast_exp2(scB[ct][r]);
                scA[ct][r] = fast_exp2(scA[ct][r]);
            }

#pragma unroll
        for (int ct = 0; ct < 4; ++ct)
#pragma unroll
            for (int r = 0; r < 4; ++r) {
                const int pr = (wave * 16 + quad * 4 + r) * 72 + ct * 16 + l15;
                Ps[pr]            = (__bf16)scB[ct][r];
                Ps[64 * 72 + pr]  = (__bf16)scA[ct][r];
            }

        bf16x8 afB0 = *(const bf16x8*)&Ps[(wave * 16 + l15) * 72 + quad * 8];
        bf16x8 afB1 = *(const bf16x8*)&Ps[(wave * 16 + l15) * 72 + 32 + quad * 8];
        bf16x8 afA0 = *(const bf16x8*)&Ps[(64 + wave * 16 + l15) * 72 + quad * 8];
        bf16x8 afA1 = *(const bf16x8*)&Ps[(64 + wave * 16 + l15) * 72 + 32 + quad * 8];

        __builtin_amdgcn_s_setprio(1);
#pragma unroll
        for (int ct = 0; ct < 4; ++ct) {
            bf16x8 v0 = *(const bf16x8*)&Vs[(ct * 16 + l15) * 72 + quad * 8];
            bf16x8 v1 = *(const bf16x8*)&Vs[(ct * 16 + l15) * 72 + 32 + quad * 8];
            oB[ct] = __builtin_amdgcn_mfma_f32_16x16x32_bf16(afB0, v0, oB[ct], 0, 0, 0);
            oB[ct] = __builtin_amdgcn_mfma_f32_16x16x32_bf16(afB1, v1, oB[ct], 0, 0, 0);
            oA[ct] = __builtin_amdgcn_mfma_f32_16x16x32_bf16(afA0, v0, oA[ct], 0, 0, 0);
            oA[ct] = __builtin_amdgcn_mfma_f32_16x16x32_bf16(afA1, v1, oA[ct], 0, 0, 0);
        }
        olB = __builtin_amdgcn_mfma_f32_16x16x32_bf16(afB0, ones, olB, 0, 0, 0);
        olB = __builtin_amdgcn_mfma_f32_16x16x32_bf16(afB1, ones, olB, 0, 0, 0);
        olA = __builtin_amdgcn_mfma_f32_16x16x32_bf16(afA0, ones, olA, 0, 0, 0);
        olA = __builtin_amdgcn_mfma_f32_16x16x32_bf16(afA1, ones, olA, 0, 0, 0);
        __builtin_amdgcn_s_setprio(0);
    };

    for (int kt = 0; kt <= qtB; ++kt) {
        __syncthreads();
#pragma unroll
        for (int i = 0; i < 2; ++i) {
            int row = srow0 + i * 32;
            *(bf16x8*)&Ks[row * 72 + scol] = kreg[i];
            *(bf16x8*)&Vs[row * 72 + scol] = vreg[i];
        }
        __syncthreads();

        {
            const int kvn = (kt < qtB ? kt + 1 : kt) * 64;
#pragma unroll
            for (int i = 0; i < 2; ++i) {
                int row = srow0 + i * 32;
                kreg[i] = *(const bf16x8*)&Kg[(size_t)(kvn + row) * DH + scol];
                vreg[i] = *(const bf16x8*)&Vtg[(size_t)row * SEQ + kvn + scol];
            }
        }

        if (kt <= qtA)                 // block-uniform; kt<=qtA<qtB => no B diag
            merged_step(kt == qtA);
        else
            half_stepB(kt == qtB);
    }

    // epilogue: normalize (v_rcp), write concat[b][s][h*64+d]
#pragma unroll
    for (int ct = 0; ct < 4; ++ct)
#pragma unroll
        for (int r = 0; r < 4; ++r) {
            int rr = wave * 16 + quad * 4 + r;
            int sA = qtA * 64 + rr;
            int sB = qtB * 64 + rr;
            Cat[((size_t)(b * SEQ + sA)) * DM + h * DH + ct * 16 + l15] =
                (__bf16)(oA[ct][r] * fast_rcp(olA[r]));
            Cat[((size_t)(b * SEQ + sB)) * DM + h * DH + ct * 16 + l15] =
                (__bf16)(oB[ct][r] * fast_rcp(olB[r]));
        }
}

// ---------------------------------------------------------------------------
// Kernel 3: output projection — exact R9/R12 form: grid (64,8)
// rowTile-fast, BK=32, async16 staging. (unchanged — control)
// ---------------------------------------------------------------------------
__global__ __launch_bounds__(256)
void oproj_kernel(const __bf16* __restrict__ A,
                  const __bf16* __restrict__ Wot,
                  float* __restrict__ C)
{
    const int rowTile = blockIdx.x;  // 0..63
    const int colTile = blockIdx.y;  // 0..7
    const int r0 = rowTile * 128;
    const int n0 = colTile * 128;

    __shared__ __align__(16) __bf16 As[128 * 32];
    __shared__ __align__(16) __bf16 Bs[128 * 32];

    const int t    = threadIdx.x;
    const int wave = t >> 6;
    const int lane = t & 63;
    const int l15  = lane & 15;
    const int quad = lane >> 4;

    f32x4 acc[2][8];
#pragma unroll
    for (int s = 0; s < 2; ++s)
#pragma unroll
        for (int i = 0; i < 8; ++i) acc[s][i] = (f32x4){0.f, 0.f, 0.f, 0.f};

    const int lrow = lane >> 2;
    const int lcol = (lane & 3) * 8;

    for (int k0 = 0; k0 < DM; k0 += 32) {
        __syncthreads();
#pragma unroll
        for (int c = 0; c < 2; ++c) {
            const int rb = wave * 32 + c * 16;
            async16(&A  [(size_t)(r0 + rb + lrow) * DM + k0 + lcol], &As[rb * 32]);
            async16(&Wot[(size_t)(n0 + rb + lrow) * DM + k0 + lcol], &Bs[rb * 32]);
        }
        __syncthreads();

        bf16x8 a0 = *(const bf16x8*)&As[(wave * 16 + l15) * 32 + quad * 8];
        bf16x8 a1 = *(const bf16x8*)&As[(64 + wave * 16 + l15) * 32 + quad * 8];
#pragma unroll
        for (int ct = 0; ct < 8; ++ct) {
            bf16x8 bb = *(const bf16x8*)&Bs[(ct * 16 + l15) * 32 + quad * 8];
            acc[0][ct] = __builtin_amdgcn_mfma_f32_16x16x32_bf16(a0, bb, acc[0][ct], 0, 0, 0);
            acc[1][ct] = __builtin_amdgcn_mfma_f32_16x16x32_bf16(a1, bb, acc[1][ct], 0, 0, 0);
        }
    }

#pragma unroll
    for (int st = 0; st < 2; ++st)
#pragma unroll
        for (int ct = 0; ct < 8; ++ct)
#pragma unroll
            for (int reg = 0; reg < 4; ++reg) {
                int r = r0 + st * 64 + wave * 16 + quad * 4 + reg;
                int n = n0 + ct * 16 + l15;
                C[(size_t)r * DM + n] = acc[st][ct][reg];
            }
}

// ---------------------------------------------------------------------------
extern "C" void kernel_launch(void* const* d_in, const int* in_sizes, int n_in,
                              void* d_out, int out_size, void* d_ws, size_t ws_size,
                              hipStream_t stream)
{
    (void)in_sizes; (void)n_in; (void)out_size; (void)ws_size;
    const float* X  = (const float*)d_in[0];
    const float* Wq = (const float*)d_in[1];
    const float* Wk = (const float*)d_in[2];
    const float* Wv = (const float*)d_in[3];
    const float* Wo = (const float*)d_in[4];
    float* out = (float*)d_out;

    char* ws = (char*)d_ws;
    const size_t wqkv_b = (size_t)NH * DM * DH * sizeof(__bf16);          // 2 MiB
    const size_t wo_b   = (size_t)DM * DM * sizeof(__bf16);               // 2 MiB
    const size_t big_b  = (size_t)BATCH * NH * SEQ * DH * sizeof(__bf16); // 16 MiB
    __bf16* Wqt = (__bf16*)(ws);                      // Wqt/Wkt/Wvt contiguous = Wcat[3072][1024]
    __bf16* Wkt = (__bf16*)(ws + wqkv_b);
    __bf16* Wvt = (__bf16*)(ws + 2 * wqkv_b);
    __bf16* Wot = (__bf16*)(ws + 3 * wqkv_b);
    __bf16* Qb  = (__bf16*)(ws + 3 * wqkv_b + wo_b);
    __bf16* Kb  = (__bf16*)(ws + 3 * wqkv_b + wo_b + big_b);
    __bf16* Vtb = (__bf16*)(ws + 3 * wqkv_b + wo_b + 2 * big_b);
    __bf16* Cat = (__bf16*)(ws + 3 * wqkv_b + wo_b + 3 * big_b);
    __bf16* Xb  = (__bf16*)(ws + 3 * wqkv_b + wo_b + 4 * big_b);

    prep_kernel<<<dim3(4096 + 768 + 256), 256, 0, stream>>>(
        X, Wq, Wk, Wv, Wo, Xb, Wqt, Wkt, Wvt, Wot);
    qkv_gemm<<<dim3(64, 24), 256, 0, stream>>>(Xb, Wqt, Qb, Kb, Vtb);
    attn_kernel<<<dim3(64, 16), 256, 0, stream>>>(Qb, Kb, Vtb, Cat);
    oproj_kernel<<<dim3(64, 8), 256, 0, stream>>>(Cat, Wot, out);
}